// Round 6
// baseline (377.414 us; speedup 1.0000x reference)
//
#include <hip/hip_runtime.h>
#include <math.h>

#define BATCH 8192
#define HDIM  1024
#define KDIM  2048
#define NDIM  3072

typedef __attribute__((ext_vector_type(8))) short short8;
typedef __attribute__((ext_vector_type(4))) float floatx4;

__device__ __forceinline__ float b2f(unsigned short u) {
  union { unsigned int i; float f; } v; v.i = ((unsigned int)u) << 16; return v.f;
}
__device__ __forceinline__ unsigned short f2b(float f) {
  union { unsigned int i; float f; } v; v.f = f;
  unsigned int r = v.i + 0x7FFFu + ((v.i >> 16) & 1u);
  return (unsigned short)(r >> 16);
}
__device__ __forceinline__ float ldsel(const void* p, size_t i, int isbf) {
  return isbf ? b2f(((const unsigned short*)p)[i]) : ((const float*)p)[i];
}
__device__ __forceinline__ float sigf(float x) { return 1.0f / (1.0f + __expf(-x)); }
__device__ __forceinline__ float tanhfast(float x) {
  float a = __builtin_fabsf(x);
  float t = __expf(-2.f * a);
  float r = (1.f - t) / (1.f + t);
  return copysignf(r, x);
}

// wave-uniform dtype detect from x[0..63]
__device__ __forceinline__ int detect_bf(const void* x) {
  unsigned int w = ((const unsigned int*)x)[threadIdx.x & 63];
  unsigned short lo = (unsigned short)(w & 0xFFFFu);
  int e = (lo >> 7) & 0xFF;
  bool ok = (e >= 110 && e <= 135) || ((lo & 0x7FFFu) == 0);
  unsigned long long m = __ballot(ok);
  return (__popcll(m) >= 48) ? 1 : 0;
}

// async 16B global->LDS
__device__ __forceinline__ void gld16(const void* g, void* l) {
  auto gp = reinterpret_cast<__attribute__((address_space(1))) unsigned int*>(
      (unsigned long long)g);
  auto lp = reinterpret_cast<__attribute__((address_space(3))) unsigned int*>(
      (unsigned long long)l);
  __builtin_amdgcn_global_load_lds(gp, lp, 16, 0, 0);
}

// load 8 bf16 (as short8) from either-format source at element offset
__device__ __forceinline__ short8 ld8bf(const void* p, size_t off, int isbf) {
  short8 r;
  if (isbf) {
    r = *(const short8*)((const unsigned short*)p + off);
  } else {
    const float* s = (const float*)p + off;
    float4 a = *(const float4*)(s);
    float4 b = *(const float4*)(s + 4);
    r[0]=(short)f2b(a.x); r[1]=(short)f2b(a.y); r[2]=(short)f2b(a.z); r[3]=(short)f2b(a.w);
    r[4]=(short)f2b(b.x); r[5]=(short)f2b(b.y); r[6]=(short)f2b(b.z); r[7]=(short)f2b(b.w);
  }
  return r;
}

// load 8 floats from either-format source at element offset
__device__ __forceinline__ void ld8f(const void* p, size_t off, int isbf, float* o) {
  if (isbf) {
    short8 s = *(const short8*)((const unsigned short*)p + off);
#pragma unroll
    for (int j = 0; j < 8; ++j) o[j] = b2f((unsigned short)s[j]);
  } else {
    const float* s = (const float*)p + off;
    float4 a = *(const float4*)(s);
    float4 b = *(const float4*)(s + 4);
    o[0]=a.x; o[1]=a.y; o[2]=a.z; o[3]=a.w;
    o[4]=b.x; o[5]=b.y; o[6]=b.z; o[7]=b.w;
  }
}

// =============================================================== k_pre
// blocks [0,512): prep (z1/z2 MLP + A-pack). [512,2048): WT pack. (R5 verified)
__global__ __launch_bounds__(256) void k_pre(
    const void* __restrict__ x, const void* __restrict__ h,
    const void* __restrict__ W1, const void* __restrict__ b1,
    const void* __restrict__ W2, const void* __restrict__ b2,
    const void* __restrict__ wxi, const void* __restrict__ whi,
    const void* __restrict__ wxc, const void* __restrict__ whc,
    const void* __restrict__ wxo, const void* __restrict__ who,
    unsigned short* __restrict__ A, unsigned short* __restrict__ WT,
    float* __restrict__ z2) {
  __shared__ __align__(16) char smem[21888];
  const int isbf = detect_bf(x);
  const int tid = threadIdx.x;
  const int bx = blockIdx.x;

  if (bx < 512) {
    char* tAb = smem;                      // [16][256] bf16 swz = 8 KB
    char* tBb = smem + 8192;               // [16][256] bf16 swz = 8 KB
    float* part = (float*)(smem + 16384);  // [4][16][17]
    float* z1s  = (float*)(smem + 20736);  // [16][17]
    const int m0 = bx * 16;
    const int lane = tid & 63;
    const int w = tid >> 6;
    const int q = lane >> 4;
    const int r = lane & 15;
    const int arow = tid >> 4;          // 0..15
    const int ak = (tid & 15) * 16;     // 0..240

    floatx4 acc = {0.f, 0.f, 0.f, 0.f};

    for (int ktile = 0; ktile < 8; ++ktile) {
      const int k0 = ktile * 256;
      const void* src = (k0 < 1024) ? x : h;
      const int klocal = (k0 & 1023) + ak;
      short8 v0 = ld8bf(src, (size_t)(m0 + arow) * 1024 + klocal, isbf);
      short8 v1 = ld8bf(src, (size_t)(m0 + arow) * 1024 + klocal + 8, isbf);
      float wv[16];
      if (isbf) {
        const unsigned short* s = (const unsigned short*)W1 + (size_t)(k0 + tid) * 16;
        short8 s0 = *(const short8*)(s);
        short8 s1 = *(const short8*)(s + 8);
#pragma unroll
        for (int j = 0; j < 8; ++j) { wv[j] = b2f((unsigned short)s0[j]);
                                      wv[8 + j] = b2f((unsigned short)s1[j]); }
      } else {
        const float* s = (const float*)W1 + (size_t)(k0 + tid) * 16;
        float4 a0 = *(const float4*)(s);
        float4 a1 = *(const float4*)(s + 4);
        float4 a2 = *(const float4*)(s + 8);
        float4 a3 = *(const float4*)(s + 12);
        wv[0]=a0.x; wv[1]=a0.y; wv[2]=a0.z; wv[3]=a0.w;
        wv[4]=a1.x; wv[5]=a1.y; wv[6]=a1.z; wv[7]=a1.w;
        wv[8]=a2.x; wv[9]=a2.y; wv[10]=a2.z; wv[11]=a2.w;
        wv[12]=a3.x; wv[13]=a3.y; wv[14]=a3.z; wv[15]=a3.w;
      }
      if (!isbf) {
        unsigned short* Ao = A + (size_t)(m0 + arow) * KDIM + k0 + ak;
        *(short8*)(Ao) = v0;
        *(short8*)(Ao + 8) = v1;
      }
      {
        const int base = arow * 512 + ak * 2;
        const int sw = (arow & 7) << 4;
        *(short8*)(tAb + ((base) ^ sw)) = v0;
        *(short8*)(tAb + ((base + 16) ^ sw)) = v1;
      }
#pragma unroll
      for (int j = 0; j < 16; ++j) {
        *(unsigned short*)(tBb + ((j * 512 + tid * 2) ^ ((j & 7) << 4))) = f2b(wv[j]);
      }
      __syncthreads();
#pragma unroll
      for (int s = 0; s < 2; ++s) {
        const int ks = (w * 2 + s) * 32 + q * 8;
        short8 af = *(const short8*)(tAb + ((r * 512 + ks * 2) ^ ((r & 7) << 4)));
        short8 bf = *(const short8*)(tBb + ((r * 512 + ks * 2) ^ ((r & 7) << 4)));
        acc = __builtin_amdgcn_mfma_f32_16x16x32_bf16(af, bf, acc, 0, 0, 0);
      }
      __syncthreads();
    }
#pragma unroll
    for (int t = 0; t < 4; ++t) part[(w * 16 + q * 4 + t) * 17 + r] = acc[t];
    __syncthreads();
    {
      const int row = tid >> 4;
      const int n = tid & 15;
      float s = part[(0 * 16 + row) * 17 + n] + part[(1 * 16 + row) * 17 + n] +
                part[(2 * 16 + row) * 17 + n] + part[(3 * 16 + row) * 17 + n] +
                ldsel(b1, (size_t)n, isbf);
      z1s[row * 17 + n] = fmaxf(s, 0.f);
    }
    __syncthreads();
    if (tid < 128) {
      const int row = tid >> 3;
      const int p = tid & 7;
      float s = ldsel(b2, (size_t)p, isbf);
#pragma unroll
      for (int nn = 0; nn < 16; ++nn)
        s += z1s[row * 17 + nn] * ldsel(W2, (size_t)nn * 8 + p, isbf);
      z2[(size_t)(m0 + row) * 8 + p] = fmaxf(s, 0.f);
    }
  } else {
    float (*tbuf)[65] = (float(*)[65])smem;   // 16640 B
    const int b = bx - 512;
    const int mat = b >> 8;
    const int rem = b & 255;
    const int ti = rem >> 4;
    const int tj = rem & 15;
    const void* Ws[6] = {wxi, whi, wxc, whc, wxo, who};
    const void* W = Ws[mat];
    const int gt = mat >> 1;
    const int half = mat & 1;
    const int rrow = tid >> 3;
    const int c8 = (tid & 7) * 8;
#pragma unroll
    for (int it = 0; it < 2; ++it) {
      int row = it * 32 + rrow;
      size_t off = (size_t)(ti * 64 + row) * 1024 + tj * 64 + c8;
      if (isbf) {
        const unsigned short* s = (const unsigned short*)W + off;
        ushort4 a = *(const ushort4*)(s);
        ushort4 bv = *(const ushort4*)(s + 4);
        tbuf[row][c8+0]=b2f(a.x);  tbuf[row][c8+1]=b2f(a.y);
        tbuf[row][c8+2]=b2f(a.z);  tbuf[row][c8+3]=b2f(a.w);
        tbuf[row][c8+4]=b2f(bv.x); tbuf[row][c8+5]=b2f(bv.y);
        tbuf[row][c8+6]=b2f(bv.z); tbuf[row][c8+7]=b2f(bv.w);
      } else {
        const float* s = (const float*)W + off;
        float4 a = *(const float4*)(s);
        float4 bv = *(const float4*)(s + 4);
        tbuf[row][c8+0]=a.x;  tbuf[row][c8+1]=a.y;  tbuf[row][c8+2]=a.z;  tbuf[row][c8+3]=a.w;
        tbuf[row][c8+4]=bv.x; tbuf[row][c8+5]=bv.y; tbuf[row][c8+6]=bv.z; tbuf[row][c8+7]=bv.w;
      }
    }
    __syncthreads();
#pragma unroll
    for (int it = 0; it < 2; ++it) {
      int nl = it * 32 + rrow;
      int n = gt * 1024 + tj * 64 + nl;
      int kk = half * 1024 + ti * 64 + c8;
      short8 pk;
#pragma unroll
      for (int i = 0; i < 8; ++i) pk[i] = (short)f2b(tbuf[c8 + i][nl]);
      *(short8*)(WT + (size_t)n * KDIM + kk) = pk;
    }
  }
}

// =============================================================== k_gemm
// 256x128 tile, 512 threads (8 waves = 4Mx2N, 64x64 each), BK=64 as two 32-k
// halves in a 4-slot LDS ring (96 KB). 4 sub-phases per K-tile, counted
// vmcnt(3) once per K-tile (3 loads stay in flight across barriers), setprio
// around MFMA clusters. Staging uses pre-swizzled global source + linear LDS
// dest (gld16); reads use the matching swizzle (2-way aliasing per 16-lane
// quarter = free).
__device__ __forceinline__ void stage_a(char* smem, const unsigned short* Ax,
    const unsigned short* Ah, int sA, int m0, int tid, int n) {
  const int kb = (n >> 1) * 64 + (n & 1) * 32;
  const unsigned short* sp = (kb < 1024) ? (Ax + kb) : (Ah + (kb - 1024));
#pragma unroll
  for (int j = 0; j < 2; ++j) {
    const int d = j * 512 + tid;
    const int row = d >> 2;
    const int q = (d & 3) ^ ((row >> 1) & 3);
    gld16(sp + (size_t)(m0 + row) * sA + q * 8,
          smem + ((n & 3) << 14) + d * 16);
  }
}
__device__ __forceinline__ void stage_b(char* smem, const unsigned short* WT,
    int n0, int tid, int n) {
  const int kb = (n >> 1) * 64 + (n & 1) * 32;
  const int row = tid >> 2;
  const int q = (tid & 3) ^ ((row >> 1) & 3);
  gld16(WT + (size_t)(n0 + row) * (size_t)KDIM + kb + q * 8,
        smem + 65536 + ((n & 3) << 13) + tid * 16);
}

__global__ __launch_bounds__(512, 2) void k_gemm(
    const void* __restrict__ x, const void* __restrict__ h,
    const unsigned short* __restrict__ Apack,
    const unsigned short* __restrict__ WT,
    unsigned short* __restrict__ P) {
  __shared__ __align__(16) char smem[98304];  // A: 4x16KB ring, B: 4x8KB ring
  const int isbf = detect_bf(x);
  const unsigned short* Ax = isbf ? (const unsigned short*)x : Apack;
  const unsigned short* Ah = isbf ? (const unsigned short*)h : (Apack + 1024);
  const int sA = isbf ? 1024 : KDIM;
  const int tid = threadIdx.x;
  const int lane = tid & 63;
  const int wv = tid >> 6;
  const int wm = (wv >> 1) << 6;   // 0,64,128,192
  const int wn = (wv & 1) << 6;    // 0,64
  const int m0 = blockIdx.y << 8;  // 256-row panel
  const int n0 = blockIdx.x << 7;  // 128-col panel
  const int ln15 = lane & 15;
  const int cp = (((lane >> 4) ^ ((ln15 >> 1) & 3)) & 3) << 4;  // chunk byte off

  floatx4 acc[4][4];
  const floatx4 fzero = {0.f, 0.f, 0.f, 0.f};
#pragma unroll
  for (int i = 0; i < 4; ++i)
#pragma unroll
    for (int j = 0; j < 4; ++j) acc[i][j] = fzero;

  // prologue: stage half-tiles n=0,1,2 (A:2 loads, B:1 load each)
  stage_a(smem, Ax, Ah, sA, m0, tid, 0);
  stage_b(smem, WT, n0, tid, 0);
  stage_a(smem, Ax, Ah, sA, m0, tid, 1);
  stage_b(smem, WT, n0, tid, 1);
  stage_a(smem, Ax, Ah, sA, m0, tid, 2);
  stage_b(smem, WT, n0, tid, 2);
  asm volatile("s_waitcnt vmcnt(3)" ::: "memory");  // n=0,1 landed; n=2 in flight
  __builtin_amdgcn_s_barrier();

  short8 af[4];
  for (int t = 0; t < 32; ++t) {
    const int na = 2 * t + 3;
    const int nb = 2 * t + 4;
#pragma unroll
    for (int kh = 0; kh < 2; ++kh) {
      const int sl = (2 * t + kh) & 3;
      const char* Ab = smem + (sl << 14);
      const char* Bb = smem + 65536 + (sl << 13);
      const int ns = kh ? nb : na;
      // --- sub-phase 1: ni 0,1
#pragma unroll
      for (int mi = 0; mi < 4; ++mi)
        af[mi] = *(const short8*)(Ab + ((wm + mi * 16 + ln15) << 6) + cp);
      short8 b0 = *(const short8*)(Bb + ((wn + ln15) << 6) + cp);
      short8 b1 = *(const short8*)(Bb + ((wn + 16 + ln15) << 6) + cp);
      if (ns <= 63) stage_a(smem, Ax, Ah, sA, m0, tid, ns);
      __builtin_amdgcn_s_setprio(1);
#pragma unroll
      for (int mi = 0; mi < 4; ++mi) {
        acc[mi][0] = __builtin_amdgcn_mfma_f32_16x16x32_bf16(af[mi], b0, acc[mi][0], 0, 0, 0);
        acc[mi][1] = __builtin_amdgcn_mfma_f32_16x16x32_bf16(af[mi], b1, acc[mi][1], 0, 0, 0);
      }
      __builtin_amdgcn_s_setprio(0);
      asm volatile("s_barrier" ::: "memory");
      // --- sub-phase 2: ni 2,3 (af reused)
      b0 = *(const short8*)(Bb + ((wn + 32 + ln15) << 6) + cp);
      b1 = *(const short8*)(Bb + ((wn + 48 + ln15) << 6) + cp);
      if (ns <= 63) stage_b(smem, WT, n0, tid, ns);
      __builtin_amdgcn_s_setprio(1);
#pragma unroll
      for (int mi = 0; mi < 4; ++mi) {
        acc[mi][2] = __builtin_amdgcn_mfma_f32_16x16x32_bf16(af[mi], b0, acc[mi][2], 0, 0, 0);
        acc[mi][3] = __builtin_amdgcn_mfma_f32_16x16x32_bf16(af[mi], b1, acc[mi][3], 0, 0, 0);
      }
      __builtin_amdgcn_s_setprio(0);
      if (kh) {
        if (t >= 30) asm volatile("s_waitcnt vmcnt(0)" ::: "memory");
        else         asm volatile("s_waitcnt vmcnt(3)" ::: "memory");
      }
      asm volatile("s_barrier" ::: "memory");
    }
  }

  const int col = ln15;
  const int rq = (lane >> 4) << 2;
#pragma unroll
  for (int mi = 0; mi < 4; ++mi) {
#pragma unroll
    for (int ni = 0; ni < 4; ++ni) {
      const size_t n = (size_t)(n0 + wn + (ni << 4) + col);
#pragma unroll
      for (int t = 0; t < 4; ++t) {
        const size_t m = (size_t)(m0 + wm + (mi << 4) + rq + t);
        P[m * NDIM + n] = f2b(acc[mi][ni][t]);
      }
    }
  }
}

// =============================================================== k_pointwise
// 2048 blocks x 4 rows; 8 cols/thread -> 16B loads/stores. (R5 verified)
__global__ __launch_bounds__(256) void k_pointwise(
    const unsigned short* __restrict__ P, const void* __restrict__ x,
    const void* __restrict__ cin,
    const void* __restrict__ bi, const void* __restrict__ bc,
    const void* __restrict__ bo, const float* __restrict__ z2,
    const void* __restrict__ W3, const void* __restrict__ b3,
    void* __restrict__ out) {
  const int isbf = detect_bf(x);
  const int tid = threadIdx.x;
  const int n = (tid & 127) * 8;
  const int rhalf = tid >> 7;
  const size_t MH = (size_t)BATCH * HDIM;

  short8 w3p[8];
  float bif[8], bcf[8], bof[8], b3f[8];
  if (isbf) {
#pragma unroll
    for (int j = 0; j < 8; ++j)
      w3p[j] = *(const short8*)((const unsigned short*)W3 + j * 1024 + n);
  } else {
#pragma unroll
    for (int j = 0; j < 8; ++j) {
      const float* s = (const float*)W3 + j * 1024 + n;
      float4 a = *(const float4*)(s);
      float4 b = *(const float4*)(s + 4);
      short8 pk;
      pk[0]=(short)f2b(a.x); pk[1]=(short)f2b(a.y); pk[2]=(short)f2b(a.z); pk[3]=(short)f2b(a.w);
      pk[4]=(short)f2b(b.x); pk[5]=(short)f2b(b.y); pk[6]=(short)f2b(b.z); pk[7]=(short)f2b(b.w);
      w3p[j] = pk;
    }
  }
  ld8f(bi, (size_t)n, isbf, bif);
  ld8f(bc, (size_t)n, isbf, bcf);
  ld8f(bo, (size_t)n, isbf, bof);
  ld8f(b3, (size_t)n, isbf, b3f);

  const size_t mbase = (size_t)blockIdx.x * 4 + rhalf;
#pragma unroll
  for (int rI = 0; rI < 2; ++rI) {
    const size_t m = mbase + rI * 2;
    const size_t idx = m * HDIM + n;
    const unsigned short* pr = P + m * NDIM + n;
    short8 ui = *(const short8*)(pr);
    short8 ug = *(const short8*)(pr + 1024);
    short8 uo = *(const short8*)(pr + 2048);
    float4 za = *(const float4*)(z2 + m * 8);
    float4 zb = *(const float4*)(z2 + m * 8 + 4);
    float zz[8] = {za.x, za.y, za.z, za.w, zb.x, zb.y, zb.z, zb.w};
    float cf[8];
    ld8f(cin, idx, isbf, cf);
    float hn[8], cn[8], ff[8];
#pragma unroll
    for (int t = 0; t < 8; ++t) {
      float f3 = b3f[t];
#pragma unroll
      for (int j = 0; j < 8; ++j) f3 += zz[j] * b2f((unsigned short)w3p[j][t]);
      const float F = sigf(f3);
      const float I = sigf(b2f((unsigned short)ui[t]) + bif[t]);
      const float G = tanhfast(b2f((unsigned short)ug[t]) + bcf[t]);
      const float O = sigf(b2f((unsigned short)uo[t]) + bof[t]);
      const float C = F * cf[t] + I * G;
      ff[t] = F;
      cn[t] = C;
      hn[t] = O * tanhfast(C);
    }
    if (isbf) {
      unsigned short* ob = (unsigned short*)out;
      short8 ph, pc, pf;
#pragma unroll
      for (int t = 0; t < 8; ++t) {
        ph[t] = (short)f2b(hn[t]);
        pc[t] = (short)f2b(cn[t]);
        pf[t] = (short)f2b(ff[t]);
      }
      *(short8*)(ob + idx) = ph;
      *(short8*)(ob + MH + idx) = pc;
      *(short8*)(ob + 2 * MH + idx) = pf;
    } else {
      float* ob = (float*)out;
      *(float4*)(ob + idx)     = make_float4(hn[0], hn[1], hn[2], hn[3]);
      *(float4*)(ob + idx + 4) = make_float4(hn[4], hn[5], hn[6], hn[7]);
      *(float4*)(ob + MH + idx)     = make_float4(cn[0], cn[1], cn[2], cn[3]);
      *(float4*)(ob + MH + idx + 4) = make_float4(cn[4], cn[5], cn[6], cn[7]);
      *(float4*)(ob + 2 * MH + idx)     = make_float4(ff[0], ff[1], ff[2], ff[3]);
      *(float4*)(ob + 2 * MH + idx + 4) = make_float4(ff[4], ff[5], ff[6], ff[7]);
    }
  }
}

extern "C" void kernel_launch(void* const* d_in, const int* in_sizes, int n_in,
                              void* d_out, int out_size, void* d_ws, size_t ws_size,
                              hipStream_t stream) {
  const void* x    = d_in[0];
  const void* h    = d_in[1];
  const void* c    = d_in[2];
  const void* W_hi = d_in[3];
  const void* W_xi = d_in[4];
  const void* b_i  = d_in[5];
  const void* W_hc = d_in[6];
  const void* W_xc = d_in[7];
  const void* b_c  = d_in[8];
  const void* W_ho = d_in[9];
  const void* W_xo = d_in[10];
  const void* b_o  = d_in[11];
  const void* W1   = d_in[12];
  const void* b1   = d_in[13];
  const void* W2   = d_in[14];
  const void* b2   = d_in[15];
  const void* W3   = d_in[16];
  const void* b3   = d_in[17];

  char* ws = (char*)d_ws;
  unsigned short* A   = (unsigned short*)ws;                 // 33.5 MB (f32 path)
  unsigned short* WT  = (unsigned short*)(ws + 33554432);    // 12.6 MB
  unsigned short* P   = (unsigned short*)(ws + 46137344);    // 50.3 MB
  float*          z2b = (float*)(ws + 96468992);             // 256 KB

  k_pre<<<dim3(2048), dim3(256), 0, stream>>>(x, h, W1, b1, W2, b2,
                                              W_xi, W_hi, W_xc, W_hc, W_xo, W_ho,
                                              A, WT, z2b);
  k_gemm<<<dim3(NDIM / 128, BATCH / 256), dim3(512), 0, stream>>>(x, h, A, WT, P);
  k_pointwise<<<dim3(BATCH / 4), dim3(256), 0, stream>>>(P, x, c, b_i, b_c, b_o,
                                                         z2b, W3, b3, d_out);
}

// Round 7
// 361.811 us; speedup vs baseline: 1.0431x; 1.0431x over previous
//
#include <hip/hip_runtime.h>
#include <math.h>

#define BATCH 8192
#define HDIM  1024
#define KDIM  2048
#define NDIM  3072

typedef __attribute__((ext_vector_type(8))) short short8;
typedef __attribute__((ext_vector_type(4))) float floatx4;

__device__ __forceinline__ float b2f(unsigned short u) {
  union { unsigned int i; float f; } v; v.i = ((unsigned int)u) << 16; return v.f;
}
__device__ __forceinline__ unsigned short f2b(float f) {
  union { unsigned int i; float f; } v; v.f = f;
  unsigned int r = v.i + 0x7FFFu + ((v.i >> 16) & 1u);
  return (unsigned short)(r >> 16);
}
__device__ __forceinline__ float ldsel(const void* p, size_t i, int isbf) {
  return isbf ? b2f(((const unsigned short*)p)[i]) : ((const float*)p)[i];
}
__device__ __forceinline__ float sigf(float x) { return 1.0f / (1.0f + __expf(-x)); }
__device__ __forceinline__ float tanhfast(float x) {
  float a = __builtin_fabsf(x);
  float t = __expf(-2.f * a);
  float r = (1.f - t) / (1.f + t);
  return copysignf(r, x);
}

// wave-uniform dtype detect from x[0..63]
__device__ __forceinline__ int detect_bf(const void* x) {
  unsigned int w = ((const unsigned int*)x)[threadIdx.x & 63];
  unsigned short lo = (unsigned short)(w & 0xFFFFu);
  int e = (lo >> 7) & 0xFF;
  bool ok = (e >= 110 && e <= 135) || ((lo & 0x7FFFu) == 0);
  unsigned long long m = __ballot(ok);
  return (__popcll(m) >= 48) ? 1 : 0;
}

// async 16B global->LDS
__device__ __forceinline__ void gld16(const void* g, void* l) {
  auto gp = reinterpret_cast<__attribute__((address_space(1))) unsigned int*>(
      (unsigned long long)g);
  auto lp = reinterpret_cast<__attribute__((address_space(3))) unsigned int*>(
      (unsigned long long)l);
  __builtin_amdgcn_global_load_lds(gp, lp, 16, 0, 0);
}

// load 8 bf16 (as short8) from either-format source at element offset
__device__ __forceinline__ short8 ld8bf(const void* p, size_t off, int isbf) {
  short8 r;
  if (isbf) {
    r = *(const short8*)((const unsigned short*)p + off);
  } else {
    const float* s = (const float*)p + off;
    float4 a = *(const float4*)(s);
    float4 b = *(const float4*)(s + 4);
    r[0]=(short)f2b(a.x); r[1]=(short)f2b(a.y); r[2]=(short)f2b(a.z); r[3]=(short)f2b(a.w);
    r[4]=(short)f2b(b.x); r[5]=(short)f2b(b.y); r[6]=(short)f2b(b.z); r[7]=(short)f2b(b.w);
  }
  return r;
}

// load 8 floats from either-format source at element offset
__device__ __forceinline__ void ld8f(const void* p, size_t off, int isbf, float* o) {
  if (isbf) {
    short8 s = *(const short8*)((const unsigned short*)p + off);
#pragma unroll
    for (int j = 0; j < 8; ++j) o[j] = b2f((unsigned short)s[j]);
  } else {
    const float* s = (const float*)p + off;
    float4 a = *(const float4*)(s);
    float4 b = *(const float4*)(s + 4);
    o[0]=a.x; o[1]=a.y; o[2]=a.z; o[3]=a.w;
    o[4]=b.x; o[5]=b.y; o[6]=b.z; o[7]=b.w;
  }
}

// =============================================================== k_pre
// blocks [0,512): prep (z1/z2 MLP + A-pack). [512,2048): WT pack. (R4 verified)
__global__ __launch_bounds__(256) void k_pre(
    const void* __restrict__ x, const void* __restrict__ h,
    const void* __restrict__ W1, const void* __restrict__ b1,
    const void* __restrict__ W2, const void* __restrict__ b2,
    const void* __restrict__ wxi, const void* __restrict__ whi,
    const void* __restrict__ wxc, const void* __restrict__ whc,
    const void* __restrict__ wxo, const void* __restrict__ who,
    unsigned short* __restrict__ A, unsigned short* __restrict__ WT,
    float* __restrict__ z2) {
  __shared__ __align__(16) char smem[21888];
  const int isbf = detect_bf(x);
  const int tid = threadIdx.x;
  const int bx = blockIdx.x;

  if (bx < 512) {
    char* tAb = smem;                      // [16][256] bf16 swz = 8 KB
    char* tBb = smem + 8192;               // [16][256] bf16 swz = 8 KB
    float* part = (float*)(smem + 16384);  // [4][16][17]
    float* z1s  = (float*)(smem + 20736);  // [16][17]
    const int m0 = bx * 16;
    const int lane = tid & 63;
    const int w = tid >> 6;
    const int q = lane >> 4;
    const int r = lane & 15;
    const int arow = tid >> 4;          // 0..15
    const int ak = (tid & 15) * 16;     // 0..240

    floatx4 acc = {0.f, 0.f, 0.f, 0.f};

    for (int ktile = 0; ktile < 8; ++ktile) {
      const int k0 = ktile * 256;
      const void* src = (k0 < 1024) ? x : h;
      const int klocal = (k0 & 1023) + ak;
      short8 v0 = ld8bf(src, (size_t)(m0 + arow) * 1024 + klocal, isbf);
      short8 v1 = ld8bf(src, (size_t)(m0 + arow) * 1024 + klocal + 8, isbf);
      float wv[16];
      if (isbf) {
        const unsigned short* s = (const unsigned short*)W1 + (size_t)(k0 + tid) * 16;
        short8 s0 = *(const short8*)(s);
        short8 s1 = *(const short8*)(s + 8);
#pragma unroll
        for (int j = 0; j < 8; ++j) { wv[j] = b2f((unsigned short)s0[j]);
                                      wv[8 + j] = b2f((unsigned short)s1[j]); }
      } else {
        const float* s = (const float*)W1 + (size_t)(k0 + tid) * 16;
        float4 a0 = *(const float4*)(s);
        float4 a1 = *(const float4*)(s + 4);
        float4 a2 = *(const float4*)(s + 8);
        float4 a3 = *(const float4*)(s + 12);
        wv[0]=a0.x; wv[1]=a0.y; wv[2]=a0.z; wv[3]=a0.w;
        wv[4]=a1.x; wv[5]=a1.y; wv[6]=a1.z; wv[7]=a1.w;
        wv[8]=a2.x; wv[9]=a2.y; wv[10]=a2.z; wv[11]=a2.w;
        wv[12]=a3.x; wv[13]=a3.y; wv[14]=a3.z; wv[15]=a3.w;
      }
      if (!isbf) {
        unsigned short* Ao = A + (size_t)(m0 + arow) * KDIM + k0 + ak;
        *(short8*)(Ao) = v0;
        *(short8*)(Ao + 8) = v1;
      }
      {
        const int base = arow * 512 + ak * 2;
        const int sw = (arow & 7) << 4;
        *(short8*)(tAb + ((base) ^ sw)) = v0;
        *(short8*)(tAb + ((base + 16) ^ sw)) = v1;
      }
#pragma unroll
      for (int j = 0; j < 16; ++j) {
        *(unsigned short*)(tBb + ((j * 512 + tid * 2) ^ ((j & 7) << 4))) = f2b(wv[j]);
      }
      __syncthreads();
#pragma unroll
      for (int s = 0; s < 2; ++s) {
        const int ks = (w * 2 + s) * 32 + q * 8;
        short8 af = *(const short8*)(tAb + ((r * 512 + ks * 2) ^ ((r & 7) << 4)));
        short8 bf = *(const short8*)(tBb + ((r * 512 + ks * 2) ^ ((r & 7) << 4)));
        acc = __builtin_amdgcn_mfma_f32_16x16x32_bf16(af, bf, acc, 0, 0, 0);
      }
      __syncthreads();
    }
#pragma unroll
    for (int t = 0; t < 4; ++t) part[(w * 16 + q * 4 + t) * 17 + r] = acc[t];
    __syncthreads();
    {
      const int row = tid >> 4;
      const int n = tid & 15;
      float s = part[(0 * 16 + row) * 17 + n] + part[(1 * 16 + row) * 17 + n] +
                part[(2 * 16 + row) * 17 + n] + part[(3 * 16 + row) * 17 + n] +
                ldsel(b1, (size_t)n, isbf);
      z1s[row * 17 + n] = fmaxf(s, 0.f);
    }
    __syncthreads();
    if (tid < 128) {
      const int row = tid >> 3;
      const int p = tid & 7;
      float s = ldsel(b2, (size_t)p, isbf);
#pragma unroll
      for (int nn = 0; nn < 16; ++nn)
        s += z1s[row * 17 + nn] * ldsel(W2, (size_t)nn * 8 + p, isbf);
      z2[(size_t)(m0 + row) * 8 + p] = fmaxf(s, 0.f);
    }
  } else {
    float (*tbuf)[65] = (float(*)[65])smem;   // 16640 B
    const int b = bx - 512;
    const int mat = b >> 8;
    const int rem = b & 255;
    const int ti = rem >> 4;
    const int tj = rem & 15;
    const void* Ws[6] = {wxi, whi, wxc, whc, wxo, who};
    const void* W = Ws[mat];
    const int gt = mat >> 1;
    const int half = mat & 1;
    const int rrow = tid >> 3;
    const int c8 = (tid & 7) * 8;
#pragma unroll
    for (int it = 0; it < 2; ++it) {
      int row = it * 32 + rrow;
      size_t off = (size_t)(ti * 64 + row) * 1024 + tj * 64 + c8;
      if (isbf) {
        const unsigned short* s = (const unsigned short*)W + off;
        ushort4 a = *(const ushort4*)(s);
        ushort4 bv = *(const ushort4*)(s + 4);
        tbuf[row][c8+0]=b2f(a.x);  tbuf[row][c8+1]=b2f(a.y);
        tbuf[row][c8+2]=b2f(a.z);  tbuf[row][c8+3]=b2f(a.w);
        tbuf[row][c8+4]=b2f(bv.x); tbuf[row][c8+5]=b2f(bv.y);
        tbuf[row][c8+6]=b2f(bv.z); tbuf[row][c8+7]=b2f(bv.w);
      } else {
        const float* s = (const float*)W + off;
        float4 a = *(const float4*)(s);
        float4 bv = *(const float4*)(s + 4);
        tbuf[row][c8+0]=a.x;  tbuf[row][c8+1]=a.y;  tbuf[row][c8+2]=a.z;  tbuf[row][c8+3]=a.w;
        tbuf[row][c8+4]=bv.x; tbuf[row][c8+5]=bv.y; tbuf[row][c8+6]=bv.z; tbuf[row][c8+7]=bv.w;
      }
    }
    __syncthreads();
#pragma unroll
    for (int it = 0; it < 2; ++it) {
      int nl = it * 32 + rrow;
      int n = gt * 1024 + tj * 64 + nl;
      int kk = half * 1024 + ti * 64 + c8;
      short8 pk;
#pragma unroll
      for (int i = 0; i < 8; ++i) pk[i] = (short)f2b(tbuf[c8 + i][nl]);
      *(short8*)(WT + (size_t)n * KDIM + kk) = pk;
    }
  }
}

// =============================================================== k_gemm
// Proven R2/R4 structure (no swizzle). launch_bounds min-waves 3->4: regs are
// at the 64 arch + 64 acc = 128 boundary, so 4 waves/SIMD should fit without
// spill; raises theoretical residency to 4 blocks/CU for barrier interleave.
__global__ __launch_bounds__(256, 4) void k_gemm(
    const void* __restrict__ x, const void* __restrict__ h,
    const unsigned short* __restrict__ Apack,
    const unsigned short* __restrict__ WT,
    unsigned short* __restrict__ P) {
  const int isbf = detect_bf(x);
  const unsigned short* Ax = isbf ? (const unsigned short*)x : Apack;
  const unsigned short* Ah = isbf ? (const unsigned short*)h : (Apack + 1024);
  const int sA = isbf ? 1024 : 2048;
  __shared__ __align__(16) unsigned short lA[128 * 64];
  __shared__ __align__(16) unsigned short lB[128 * 64];
  const int tid = threadIdx.x;
  const int lane = tid & 63;
  const int wv = tid >> 6;
  const int wm = (wv >> 1) << 6;
  const int wn = (wv & 1) << 6;
  const int m0 = blockIdx.y << 7;
  const int n0 = blockIdx.x << 7;

  floatx4 acc[4][4];
  const floatx4 fzero = {0.f, 0.f, 0.f, 0.f};
#pragma unroll
  for (int i = 0; i < 4; ++i)
#pragma unroll
    for (int j = 0; j < 4; ++j) acc[i][j] = fzero;

  int rr[4], kk[4];
#pragma unroll
  for (int ps = 0; ps < 4; ++ps) {
    int chunk = ps * 256 + tid;
    rr[ps] = chunk >> 3;
    kk[ps] = (chunk & 7) ^ (rr[ps] & 7);
  }
  const int px0 = (lane >> 4) ^ (lane & 7);
  const int px1 = ((lane >> 4) + 4) ^ (lane & 7);
  const int rowA = wm + (lane & 15);
  const int rowB = wn + (lane & 15);

  for (int kt = 0; kt < KDIM / 64; ++kt) {
    const int k0 = kt * 64;
    const unsigned short* Abase = (k0 < 1024) ? (Ax + k0) : (Ah + (k0 - 1024));
#pragma unroll
    for (int ps = 0; ps < 4; ++ps) {
      const int chunk = ps * 256 + tid;
      gld16(Abase + (size_t)(m0 + rr[ps]) * sA + kk[ps] * 8, lA + chunk * 8);
      gld16(WT + ((size_t)(n0 + rr[ps]) * KDIM + k0 + kk[ps] * 8), lB + chunk * 8);
    }
    __syncthreads();
#pragma unroll
    for (int s = 0; s < 2; ++s) {
      const int px = s ? px1 : px0;
      short8 af[4], bfr[4];
#pragma unroll
      for (int i = 0; i < 4; ++i)
        af[i] = *(const short8*)(lA + ((((rowA + (i << 4)) << 3) + px) << 3));
#pragma unroll
      for (int i = 0; i < 4; ++i)
        bfr[i] = *(const short8*)(lB + ((((rowB + (i << 4)) << 3) + px) << 3));
#pragma unroll
      for (int mi = 0; mi < 4; ++mi)
#pragma unroll
        for (int ni = 0; ni < 4; ++ni)
          acc[mi][ni] = __builtin_amdgcn_mfma_f32_16x16x32_bf16(
              af[mi], bfr[ni], acc[mi][ni], 0, 0, 0);
    }
    __syncthreads();
  }
  const int col = lane & 15;
  const int rq = (lane >> 4) << 2;
#pragma unroll
  for (int mi = 0; mi < 4; ++mi) {
#pragma unroll
    for (int ni = 0; ni < 4; ++ni) {
      const size_t n = (size_t)(n0 + wn + (ni << 4) + col);
#pragma unroll
      for (int t = 0; t < 4; ++t) {
        const size_t m = (size_t)(m0 + wm + (mi << 4) + rq + t);
        P[m * NDIM + n] = f2b(acc[mi][ni][t]);
      }
    }
  }
}

// =============================================================== k_pointwise
// 1024 blocks x 8 rows; 8 cols/thread, 16B loads/stores. W3 bf16-packed in regs;
// setup (W3/bias loads) amortized over 2x rows vs R4.
__global__ __launch_bounds__(256) void k_pointwise(
    const unsigned short* __restrict__ P, const void* __restrict__ x,
    const void* __restrict__ cin,
    const void* __restrict__ bi, const void* __restrict__ bc,
    const void* __restrict__ bo, const float* __restrict__ z2,
    const void* __restrict__ W3, const void* __restrict__ b3,
    void* __restrict__ out) {
  const int isbf = detect_bf(x);
  const int tid = threadIdx.x;
  const int n = (tid & 127) * 8;
  const int rhalf = tid >> 7;
  const size_t MH = (size_t)BATCH * HDIM;

  short8 w3p[8];
  float bif[8], bcf[8], bof[8], b3f[8];
  if (isbf) {
#pragma unroll
    for (int j = 0; j < 8; ++j)
      w3p[j] = *(const short8*)((const unsigned short*)W3 + j * 1024 + n);
  } else {
#pragma unroll
    for (int j = 0; j < 8; ++j) {
      const float* s = (const float*)W3 + j * 1024 + n;
      float4 a = *(const float4*)(s);
      float4 b = *(const float4*)(s + 4);
      short8 pk;
      pk[0]=(short)f2b(a.x); pk[1]=(short)f2b(a.y); pk[2]=(short)f2b(a.z); pk[3]=(short)f2b(a.w);
      pk[4]=(short)f2b(b.x); pk[5]=(short)f2b(b.y); pk[6]=(short)f2b(b.z); pk[7]=(short)f2b(b.w);
      w3p[j] = pk;
    }
  }
  ld8f(bi, (size_t)n, isbf, bif);
  ld8f(bc, (size_t)n, isbf, bcf);
  ld8f(bo, (size_t)n, isbf, bof);
  ld8f(b3, (size_t)n, isbf, b3f);

  const size_t mbase = (size_t)blockIdx.x * 8 + rhalf;
#pragma unroll
  for (int rI = 0; rI < 4; ++rI) {
    const size_t m = mbase + rI * 2;
    const size_t idx = m * HDIM + n;
    const unsigned short* pr = P + m * NDIM + n;
    short8 ui = *(const short8*)(pr);
    short8 ug = *(const short8*)(pr + 1024);
    short8 uo = *(const short8*)(pr + 2048);
    float4 za = *(const float4*)(z2 + m * 8);
    float4 zb = *(const float4*)(z2 + m * 8 + 4);
    float zz[8] = {za.x, za.y, za.z, za.w, zb.x, zb.y, zb.z, zb.w};
    float cf[8];
    ld8f(cin, idx, isbf, cf);
    float hn[8], cn[8], ff[8];
#pragma unroll
    for (int t = 0; t < 8; ++t) {
      float f3 = b3f[t];
#pragma unroll
      for (int j = 0; j < 8; ++j) f3 += zz[j] * b2f((unsigned short)w3p[j][t]);
      const float F = sigf(f3);
      const float I = sigf(b2f((unsigned short)ui[t]) + bif[t]);
      const float G = tanhfast(b2f((unsigned short)ug[t]) + bcf[t]);
      const float O = sigf(b2f((unsigned short)uo[t]) + bof[t]);
      const float C = F * cf[t] + I * G;
      ff[t] = F;
      cn[t] = C;
      hn[t] = O * tanhfast(C);
    }
    if (isbf) {
      unsigned short* ob = (unsigned short*)out;
      short8 ph, pc, pf;
#pragma unroll
      for (int t = 0; t < 8; ++t) {
        ph[t] = (short)f2b(hn[t]);
        pc[t] = (short)f2b(cn[t]);
        pf[t] = (short)f2b(ff[t]);
      }
      *(short8*)(ob + idx) = ph;
      *(short8*)(ob + MH + idx) = pc;
      *(short8*)(ob + 2 * MH + idx) = pf;
    } else {
      float* ob = (float*)out;
      *(float4*)(ob + idx)     = make_float4(hn[0], hn[1], hn[2], hn[3]);
      *(float4*)(ob + idx + 4) = make_float4(hn[4], hn[5], hn[6], hn[7]);
      *(float4*)(ob + MH + idx)     = make_float4(cn[0], cn[1], cn[2], cn[3]);
      *(float4*)(ob + MH + idx + 4) = make_float4(cn[4], cn[5], cn[6], cn[7]);
      *(float4*)(ob + 2 * MH + idx)     = make_float4(ff[0], ff[1], ff[2], ff[3]);
      *(float4*)(ob + 2 * MH + idx + 4) = make_float4(ff[4], ff[5], ff[6], ff[7]);
    }
  }
}

extern "C" void kernel_launch(void* const* d_in, const int* in_sizes, int n_in,
                              void* d_out, int out_size, void* d_ws, size_t ws_size,
                              hipStream_t stream) {
  const void* x    = d_in[0];
  const void* h    = d_in[1];
  const void* c    = d_in[2];
  const void* W_hi = d_in[3];
  const void* W_xi = d_in[4];
  const void* b_i  = d_in[5];
  const void* W_hc = d_in[6];
  const void* W_xc = d_in[7];
  const void* b_c  = d_in[8];
  const void* W_ho = d_in[9];
  const void* W_xo = d_in[10];
  const void* b_o  = d_in[11];
  const void* W1   = d_in[12];
  const void* b1   = d_in[13];
  const void* W2   = d_in[14];
  const void* b2   = d_in[15];
  const void* W3   = d_in[16];
  const void* b3   = d_in[17];

  char* ws = (char*)d_ws;
  unsigned short* A   = (unsigned short*)ws;                 // 33.5 MB (f32 path)
  unsigned short* WT  = (unsigned short*)(ws + 33554432);    // 12.6 MB
  unsigned short* P   = (unsigned short*)(ws + 46137344);    // 50.3 MB
  float*          z2b = (float*)(ws + 96468992);             // 256 KB

  k_pre<<<dim3(2048), dim3(256), 0, stream>>>(x, h, W1, b1, W2, b2,
                                              W_xi, W_hi, W_xc, W_hc, W_xo, W_ho,
                                              A, WT, z2b);
  k_gemm<<<dim3(NDIM / 128, BATCH / 128), dim3(256), 0, stream>>>(x, h, A, WT, P);
  k_pointwise<<<dim3(BATCH / 8), dim3(256), 0, stream>>>(P, x, c, b_i, b_c, b_o,
                                                         z2b, W3, b3, d_out);
}

// Round 8
// 356.712 us; speedup vs baseline: 1.0580x; 1.0143x over previous
//
#include <hip/hip_runtime.h>
#include <math.h>

#define BATCH 8192
#define HDIM  1024
#define KDIM  2048
#define NDIM  3072

typedef __attribute__((ext_vector_type(8))) short short8;
typedef __attribute__((ext_vector_type(4))) float floatx4;

__device__ __forceinline__ float b2f(unsigned short u) {
  union { unsigned int i; float f; } v; v.i = ((unsigned int)u) << 16; return v.f;
}
__device__ __forceinline__ unsigned short f2b(float f) {
  union { unsigned int i; float f; } v; v.f = f;
  unsigned int r = v.i + 0x7FFFu + ((v.i >> 16) & 1u);
  return (unsigned short)(r >> 16);
}
__device__ __forceinline__ float ldsel(const void* p, size_t i, int isbf) {
  return isbf ? b2f(((const unsigned short*)p)[i]) : ((const float*)p)[i];
}
__device__ __forceinline__ float sigf(float x) { return 1.0f / (1.0f + __expf(-x)); }
__device__ __forceinline__ float tanhfast(float x) {
  float a = __builtin_fabsf(x);
  float t = __expf(-2.f * a);
  float r = (1.f - t) / (1.f + t);
  return copysignf(r, x);
}

// wave-uniform dtype detect from x[0..63]
__device__ __forceinline__ int detect_bf(const void* x) {
  unsigned int w = ((const unsigned int*)x)[threadIdx.x & 63];
  unsigned short lo = (unsigned short)(w & 0xFFFFu);
  int e = (lo >> 7) & 0xFF;
  bool ok = (e >= 110 && e <= 135) || ((lo & 0x7FFFu) == 0);
  unsigned long long m = __ballot(ok);
  return (__popcll(m) >= 48) ? 1 : 0;
}

// async 16B global->LDS
__device__ __forceinline__ void gld16(const void* g, void* l) {
  auto gp = reinterpret_cast<__attribute__((address_space(1))) unsigned int*>(
      (unsigned long long)g);
  auto lp = reinterpret_cast<__attribute__((address_space(3))) unsigned int*>(
      (unsigned long long)l);
  __builtin_amdgcn_global_load_lds(gp, lp, 16, 0, 0);
}

// load 8 bf16 (as short8) from either-format source at element offset
__device__ __forceinline__ short8 ld8bf(const void* p, size_t off, int isbf) {
  short8 r;
  if (isbf) {
    r = *(const short8*)((const unsigned short*)p + off);
  } else {
    const float* s = (const float*)p + off;
    float4 a = *(const float4*)(s);
    float4 b = *(const float4*)(s + 4);
    r[0]=(short)f2b(a.x); r[1]=(short)f2b(a.y); r[2]=(short)f2b(a.z); r[3]=(short)f2b(a.w);
    r[4]=(short)f2b(b.x); r[5]=(short)f2b(b.y); r[6]=(short)f2b(b.z); r[7]=(short)f2b(b.w);
  }
  return r;
}

// load 8 floats from either-format source at element offset
__device__ __forceinline__ void ld8f(const void* p, size_t off, int isbf, float* o) {
  if (isbf) {
    short8 s = *(const short8*)((const unsigned short*)p + off);
#pragma unroll
    for (int j = 0; j < 8; ++j) o[j] = b2f((unsigned short)s[j]);
  } else {
    const float* s = (const float*)p + off;
    float4 a = *(const float4*)(s);
    float4 b = *(const float4*)(s + 4);
    o[0]=a.x; o[1]=a.y; o[2]=a.z; o[3]=a.w;
    o[4]=b.x; o[5]=b.y; o[6]=b.z; o[7]=b.w;
  }
}

// =============================================================== k_pre
// blocks [0,512): prep (z1/z2 MLP + A-pack). [512,2048): WT pack. (R4 verified)
__global__ __launch_bounds__(256) void k_pre(
    const void* __restrict__ x, const void* __restrict__ h,
    const void* __restrict__ W1, const void* __restrict__ b1,
    const void* __restrict__ W2, const void* __restrict__ b2,
    const void* __restrict__ wxi, const void* __restrict__ whi,
    const void* __restrict__ wxc, const void* __restrict__ whc,
    const void* __restrict__ wxo, const void* __restrict__ who,
    unsigned short* __restrict__ A, unsigned short* __restrict__ WT,
    float* __restrict__ z2) {
  __shared__ __align__(16) char smem[21888];
  const int isbf = detect_bf(x);
  const int tid = threadIdx.x;
  const int bx = blockIdx.x;

  if (bx < 512) {
    char* tAb = smem;                      // [16][256] bf16 swz = 8 KB
    char* tBb = smem + 8192;               // [16][256] bf16 swz = 8 KB
    float* part = (float*)(smem + 16384);  // [4][16][17]
    float* z1s  = (float*)(smem + 20736);  // [16][17]
    const int m0 = bx * 16;
    const int lane = tid & 63;
    const int w = tid >> 6;
    const int q = lane >> 4;
    const int r = lane & 15;
    const int arow = tid >> 4;          // 0..15
    const int ak = (tid & 15) * 16;     // 0..240

    floatx4 acc = {0.f, 0.f, 0.f, 0.f};

    for (int ktile = 0; ktile < 8; ++ktile) {
      const int k0 = ktile * 256;
      const void* src = (k0 < 1024) ? x : h;
      const int klocal = (k0 & 1023) + ak;
      short8 v0 = ld8bf(src, (size_t)(m0 + arow) * 1024 + klocal, isbf);
      short8 v1 = ld8bf(src, (size_t)(m0 + arow) * 1024 + klocal + 8, isbf);
      float wv[16];
      if (isbf) {
        const unsigned short* s = (const unsigned short*)W1 + (size_t)(k0 + tid) * 16;
        short8 s0 = *(const short8*)(s);
        short8 s1 = *(const short8*)(s + 8);
#pragma unroll
        for (int j = 0; j < 8; ++j) { wv[j] = b2f((unsigned short)s0[j]);
                                      wv[8 + j] = b2f((unsigned short)s1[j]); }
      } else {
        const float* s = (const float*)W1 + (size_t)(k0 + tid) * 16;
        float4 a0 = *(const float4*)(s);
        float4 a1 = *(const float4*)(s + 4);
        float4 a2 = *(const float4*)(s + 8);
        float4 a3 = *(const float4*)(s + 12);
        wv[0]=a0.x; wv[1]=a0.y; wv[2]=a0.z; wv[3]=a0.w;
        wv[4]=a1.x; wv[5]=a1.y; wv[6]=a1.z; wv[7]=a1.w;
        wv[8]=a2.x; wv[9]=a2.y; wv[10]=a2.z; wv[11]=a2.w;
        wv[12]=a3.x; wv[13]=a3.y; wv[14]=a3.z; wv[15]=a3.w;
      }
      if (!isbf) {
        unsigned short* Ao = A + (size_t)(m0 + arow) * KDIM + k0 + ak;
        *(short8*)(Ao) = v0;
        *(short8*)(Ao + 8) = v1;
      }
      {
        const int base = arow * 512 + ak * 2;
        const int sw = (arow & 7) << 4;
        *(short8*)(tAb + ((base) ^ sw)) = v0;
        *(short8*)(tAb + ((base + 16) ^ sw)) = v1;
      }
#pragma unroll
      for (int j = 0; j < 16; ++j) {
        *(unsigned short*)(tBb + ((j * 512 + tid * 2) ^ ((j & 7) << 4))) = f2b(wv[j]);
      }
      __syncthreads();
#pragma unroll
      for (int s = 0; s < 2; ++s) {
        const int ks = (w * 2 + s) * 32 + q * 8;
        short8 af = *(const short8*)(tAb + ((r * 512 + ks * 2) ^ ((r & 7) << 4)));
        short8 bf = *(const short8*)(tBb + ((r * 512 + ks * 2) ^ ((r & 7) << 4)));
        acc = __builtin_amdgcn_mfma_f32_16x16x32_bf16(af, bf, acc, 0, 0, 0);
      }
      __syncthreads();
    }
#pragma unroll
    for (int t = 0; t < 4; ++t) part[(w * 16 + q * 4 + t) * 17 + r] = acc[t];
    __syncthreads();
    {
      const int row = tid >> 4;
      const int n = tid & 15;
      float s = part[(0 * 16 + row) * 17 + n] + part[(1 * 16 + row) * 17 + n] +
                part[(2 * 16 + row) * 17 + n] + part[(3 * 16 + row) * 17 + n] +
                ldsel(b1, (size_t)n, isbf);
      z1s[row * 17 + n] = fmaxf(s, 0.f);
    }
    __syncthreads();
    if (tid < 128) {
      const int row = tid >> 3;
      const int p = tid & 7;
      float s = ldsel(b2, (size_t)p, isbf);
#pragma unroll
      for (int nn = 0; nn < 16; ++nn)
        s += z1s[row * 17 + nn] * ldsel(W2, (size_t)nn * 8 + p, isbf);
      z2[(size_t)(m0 + row) * 8 + p] = fmaxf(s, 0.f);
    }
  } else {
    float (*tbuf)[65] = (float(*)[65])smem;   // 16640 B
    const int b = bx - 512;
    const int mat = b >> 8;
    const int rem = b & 255;
    const int ti = rem >> 4;
    const int tj = rem & 15;
    const void* Ws[6] = {wxi, whi, wxc, whc, wxo, who};
    const void* W = Ws[mat];
    const int gt = mat >> 1;
    const int half = mat & 1;
    const int rrow = tid >> 3;
    const int c8 = (tid & 7) * 8;
#pragma unroll
    for (int it = 0; it < 2; ++it) {
      int row = it * 32 + rrow;
      size_t off = (size_t)(ti * 64 + row) * 1024 + tj * 64 + c8;
      if (isbf) {
        const unsigned short* s = (const unsigned short*)W + off;
        ushort4 a = *(const ushort4*)(s);
        ushort4 bv = *(const ushort4*)(s + 4);
        tbuf[row][c8+0]=b2f(a.x);  tbuf[row][c8+1]=b2f(a.y);
        tbuf[row][c8+2]=b2f(a.z);  tbuf[row][c8+3]=b2f(a.w);
        tbuf[row][c8+4]=b2f(bv.x); tbuf[row][c8+5]=b2f(bv.y);
        tbuf[row][c8+6]=b2f(bv.z); tbuf[row][c8+7]=b2f(bv.w);
      } else {
        const float* s = (const float*)W + off;
        float4 a = *(const float4*)(s);
        float4 bv = *(const float4*)(s + 4);
        tbuf[row][c8+0]=a.x;  tbuf[row][c8+1]=a.y;  tbuf[row][c8+2]=a.z;  tbuf[row][c8+3]=a.w;
        tbuf[row][c8+4]=bv.x; tbuf[row][c8+5]=bv.y; tbuf[row][c8+6]=bv.z; tbuf[row][c8+7]=bv.w;
      }
    }
    __syncthreads();
#pragma unroll
    for (int it = 0; it < 2; ++it) {
      int nl = it * 32 + rrow;
      int n = gt * 1024 + tj * 64 + nl;
      int kk = half * 1024 + ti * 64 + c8;
      short8 pk;
#pragma unroll
      for (int i = 0; i < 8; ++i) pk[i] = (short)f2b(tbuf[c8 + i][nl]);
      *(short8*)(WT + (size_t)n * KDIM + kk) = pk;
    }
  }
}

// =============================================================== k_gemm
// R4 structure + LDS-staged coalesced P epilogue: acc -> LDS (bf16, XOR
// swizzle, 2-way = free) -> 16B/lane stores covering 256B-contiguous row
// segments. Removes the partial-line (32B) scalar stores whose RMW fetches
// inflated FETCH_SIZE to 149MB vs ~45MB ideal.
__global__ __launch_bounds__(256, 3) void k_gemm(
    const void* __restrict__ x, const void* __restrict__ h,
    const unsigned short* __restrict__ Apack,
    const unsigned short* __restrict__ WT,
    unsigned short* __restrict__ P) {
  const int isbf = detect_bf(x);
  const unsigned short* Ax = isbf ? (const unsigned short*)x : Apack;
  const unsigned short* Ah = isbf ? (const unsigned short*)h : (Apack + 1024);
  const int sA = isbf ? 1024 : 2048;
  __shared__ __align__(16) unsigned short lAB[2 * 128 * 64];  // 32 KB
  unsigned short* lA = lAB;
  unsigned short* lB = lAB + 128 * 64;
  const int tid = threadIdx.x;
  const int lane = tid & 63;
  const int wv = tid >> 6;
  const int wm = (wv >> 1) << 6;
  const int wn = (wv & 1) << 6;
  const int m0 = blockIdx.y << 7;
  const int n0 = blockIdx.x << 7;

  floatx4 acc[4][4];
  const floatx4 fzero = {0.f, 0.f, 0.f, 0.f};
#pragma unroll
  for (int i = 0; i < 4; ++i)
#pragma unroll
    for (int j = 0; j < 4; ++j) acc[i][j] = fzero;

  int rr[4], kk[4];
#pragma unroll
  for (int ps = 0; ps < 4; ++ps) {
    int chunk = ps * 256 + tid;
    rr[ps] = chunk >> 3;
    kk[ps] = (chunk & 7) ^ (rr[ps] & 7);
  }
  const int px0 = (lane >> 4) ^ (lane & 7);
  const int px1 = ((lane >> 4) + 4) ^ (lane & 7);
  const int rowA = wm + (lane & 15);
  const int rowB = wn + (lane & 15);

  for (int kt = 0; kt < KDIM / 64; ++kt) {
    const int k0 = kt * 64;
    const unsigned short* Abase = (k0 < 1024) ? (Ax + k0) : (Ah + (k0 - 1024));
#pragma unroll
    for (int ps = 0; ps < 4; ++ps) {
      const int chunk = ps * 256 + tid;
      gld16(Abase + (size_t)(m0 + rr[ps]) * sA + kk[ps] * 8, lA + chunk * 8);
      gld16(WT + ((size_t)(n0 + rr[ps]) * KDIM + k0 + kk[ps] * 8), lB + chunk * 8);
    }
    __syncthreads();
#pragma unroll
    for (int s = 0; s < 2; ++s) {
      const int px = s ? px1 : px0;
      short8 af[4], bfr[4];
#pragma unroll
      for (int i = 0; i < 4; ++i)
        af[i] = *(const short8*)(lA + ((((rowA + (i << 4)) << 3) + px) << 3));
#pragma unroll
      for (int i = 0; i < 4; ++i)
        bfr[i] = *(const short8*)(lB + ((((rowB + (i << 4)) << 3) + px) << 3));
#pragma unroll
      for (int mi = 0; mi < 4; ++mi)
#pragma unroll
        for (int ni = 0; ni < 4; ++ni)
          acc[mi][ni] = __builtin_amdgcn_mfma_f32_16x16x32_bf16(
              af[mi], bfr[ni], acc[mi][ni], 0, 0, 0);
    }
    __syncthreads();
  }
  // ---- epilogue: acc -> LDS (swizzled bf16) -> coalesced 16B stores
  const int col = lane & 15;
  const int rq = (lane >> 4) << 2;
#pragma unroll
  for (int mi = 0; mi < 4; ++mi) {
#pragma unroll
    for (int ni = 0; ni < 4; ++ni) {
      const int cg = wn + (ni << 4) + col;
#pragma unroll
      for (int t = 0; t < 4; ++t) {
        const int row = wm + (mi << 4) + rq + t;
        lAB[row * 128 + (cg ^ (((row >> 2) & 7) << 4))] = f2b(acc[mi][ni][t]);
      }
    }
  }
  __syncthreads();
#pragma unroll
  for (int p = 0; p < 8; ++p) {
    const int row = p * 16 + wv * 4 + (lane >> 4);
    const int cc = (lane & 15) * 8;
    short8 v = *(const short8*)(lAB + row * 128 + (cc ^ (((row >> 2) & 7) << 4)));
    *(short8*)(P + (size_t)(m0 + row) * NDIM + n0 + cc) = v;
  }
}

// =============================================================== k_pointwise
// 2048 blocks x 4 rows; 8 cols/thread -> 16B loads/stores. (R4 verified)
__global__ __launch_bounds__(256) void k_pointwise(
    const unsigned short* __restrict__ P, const void* __restrict__ x,
    const void* __restrict__ cin,
    const void* __restrict__ bi, const void* __restrict__ bc,
    const void* __restrict__ bo, const float* __restrict__ z2,
    const void* __restrict__ W3, const void* __restrict__ b3,
    void* __restrict__ out) {
  const int isbf = detect_bf(x);
  const int tid = threadIdx.x;
  const int n = (tid & 127) * 8;
  const int rhalf = tid >> 7;
  const size_t MH = (size_t)BATCH * HDIM;

  short8 w3p[8];
  float bif[8], bcf[8], bof[8], b3f[8];
  if (isbf) {
#pragma unroll
    for (int j = 0; j < 8; ++j)
      w3p[j] = *(const short8*)((const unsigned short*)W3 + j * 1024 + n);
  } else {
#pragma unroll
    for (int j = 0; j < 8; ++j) {
      const float* s = (const float*)W3 + j * 1024 + n;
      float4 a = *(const float4*)(s);
      float4 b = *(const float4*)(s + 4);
      short8 pk;
      pk[0]=(short)f2b(a.x); pk[1]=(short)f2b(a.y); pk[2]=(short)f2b(a.z); pk[3]=(short)f2b(a.w);
      pk[4]=(short)f2b(b.x); pk[5]=(short)f2b(b.y); pk[6]=(short)f2b(b.z); pk[7]=(short)f2b(b.w);
      w3p[j] = pk;
    }
  }
  ld8f(bi, (size_t)n, isbf, bif);
  ld8f(bc, (size_t)n, isbf, bcf);
  ld8f(bo, (size_t)n, isbf, bof);
  ld8f(b3, (size_t)n, isbf, b3f);

  const size_t mbase = (size_t)blockIdx.x * 4 + rhalf;
#pragma unroll
  for (int rI = 0; rI < 2; ++rI) {
    const size_t m = mbase + rI * 2;
    const size_t idx = m * HDIM + n;
    const unsigned short* pr = P + m * NDIM + n;
    short8 ui = *(const short8*)(pr);
    short8 ug = *(const short8*)(pr + 1024);
    short8 uo = *(const short8*)(pr + 2048);
    float4 za = *(const float4*)(z2 + m * 8);
    float4 zb = *(const float4*)(z2 + m * 8 + 4);
    float zz[8] = {za.x, za.y, za.z, za.w, zb.x, zb.y, zb.z, zb.w};
    float cf[8];
    ld8f(cin, idx, isbf, cf);
    float hn[8], cn[8], ff[8];
#pragma unroll
    for (int t = 0; t < 8; ++t) {
      float f3 = b3f[t];
#pragma unroll
      for (int j = 0; j < 8; ++j) f3 += zz[j] * b2f((unsigned short)w3p[j][t]);
      const float F = sigf(f3);
      const float I = sigf(b2f((unsigned short)ui[t]) + bif[t]);
      const float G = tanhfast(b2f((unsigned short)ug[t]) + bcf[t]);
      const float O = sigf(b2f((unsigned short)uo[t]) + bof[t]);
      const float C = F * cf[t] + I * G;
      ff[t] = F;
      cn[t] = C;
      hn[t] = O * tanhfast(C);
    }
    if (isbf) {
      unsigned short* ob = (unsigned short*)out;
      short8 ph, pc, pf;
#pragma unroll
      for (int t = 0; t < 8; ++t) {
        ph[t] = (short)f2b(hn[t]);
        pc[t] = (short)f2b(cn[t]);
        pf[t] = (short)f2b(ff[t]);
      }
      *(short8*)(ob + idx) = ph;
      *(short8*)(ob + MH + idx) = pc;
      *(short8*)(ob + 2 * MH + idx) = pf;
    } else {
      float* ob = (float*)out;
      *(float4*)(ob + idx)     = make_float4(hn[0], hn[1], hn[2], hn[3]);
      *(float4*)(ob + idx + 4) = make_float4(hn[4], hn[5], hn[6], hn[7]);
      *(float4*)(ob + MH + idx)     = make_float4(cn[0], cn[1], cn[2], cn[3]);
      *(float4*)(ob + MH + idx + 4) = make_float4(cn[4], cn[5], cn[6], cn[7]);
      *(float4*)(ob + 2 * MH + idx)     = make_float4(ff[0], ff[1], ff[2], ff[3]);
      *(float4*)(ob + 2 * MH + idx + 4) = make_float4(ff[4], ff[5], ff[6], ff[7]);
    }
  }
}

extern "C" void kernel_launch(void* const* d_in, const int* in_sizes, int n_in,
                              void* d_out, int out_size, void* d_ws, size_t ws_size,
                              hipStream_t stream) {
  const void* x    = d_in[0];
  const void* h    = d_in[1];
  const void* c    = d_in[2];
  const void* W_hi = d_in[3];
  const void* W_xi = d_in[4];
  const void* b_i  = d_in[5];
  const void* W_hc = d_in[6];
  const void* W_xc = d_in[7];
  const void* b_c  = d_in[8];
  const void* W_ho = d_in[9];
  const void* W_xo = d_in[10];
  const void* b_o  = d_in[11];
  const void* W1   = d_in[12];
  const void* b1   = d_in[13];
  const void* W2   = d_in[14];
  const void* b2   = d_in[15];
  const void* W3   = d_in[16];
  const void* b3   = d_in[17];

  char* ws = (char*)d_ws;
  unsigned short* A   = (unsigned short*)ws;                 // 33.5 MB (f32 path)
  unsigned short* WT  = (unsigned short*)(ws + 33554432);    // 12.6 MB
  unsigned short* P   = (unsigned short*)(ws + 46137344);    // 50.3 MB
  float*          z2b = (float*)(ws + 96468992);             // 256 KB

  k_pre<<<dim3(2048), dim3(256), 0, stream>>>(x, h, W1, b1, W2, b2,
                                              W_xi, W_hi, W_xc, W_hc, W_xo, W_ho,
                                              A, WT, z2b);
  k_gemm<<<dim3(NDIM / 128, BATCH / 128), dim3(256), 0, stream>>>(x, h, A, WT, P);
  k_pointwise<<<dim3(BATCH / 4), dim3(256), 0, stream>>>(P, x, c, b_i, b_c, b_o,
                                                         z2b, W3, b3, d_out);
}